// Round 1
// 382.275 us; speedup vs baseline: 1.0732x; 1.0732x over previous
//
#include <hip/hip_runtime.h>

// Stride-2 valid conv as implicit GEMM on MFMA (bf16 in, fp32 acc).
// GEMM: M=cout=256, N=b*oh*ow=96800, K=tap*cin=1152.
// R4: conv rebuilt on the proven 8-phase-class schedule (T2 swizzle + counted
//     vmcnt(7) + setprio): BM=256 x BN=192, BK=64, 8 waves, dbuf 112KB LDS,
//     grid=505 (98.6% last-wave efficiency). relayout_w fused into relayout_x;
//     relayout_x phase-1 pair-writes + slot rotation (bank-conflict fix).

#define BATCH 32
#define CIN   128
#define H     112
#define W     112
#define COUT  256
#define OH    55
#define OW    55
#define NPIX  (OH*OW)          // 3025
#define NTOT  (BATCH*NPIX)     // 96800

#define BN    192
#define NBLK  ((NTOT + BN - 1) / BN)   // 505

typedef __bf16 bf16x8 __attribute__((ext_vector_type(8)));
typedef float  f32x4  __attribute__((ext_vector_type(4)));

__device__ __forceinline__ unsigned short f2bf(float f) {
    unsigned u = __float_as_uint(f);
    u += 0x7FFFu + ((u >> 16) & 1u);   // RNE
    return (unsigned short)(u >> 16);
}

__device__ __forceinline__ void gld_lds16(const void* g, void* l) {
    __builtin_amdgcn_global_load_lds((__attribute__((address_space(1))) void*)g,
                                     (__attribute__((address_space(3))) void*)l,
                                     16, 0, 0);
}

// ---------- fused prepass ----------
// blocks [0, BATCH*H): x NCHW fp32 -> xs[b][h][w][c] bf16 (LDS transpose)
// blocks [BATCH*H, +1152): w (COUT,CIN,3,3) fp32 -> wt[tap][cout][cin] bf16
#define XP 136   // LDS pitch in shorts (272 B, 16-B aligned)
#define WBLK ((9*COUT*CIN + 255)/256)  // 1152
__global__ __launch_bounds__(256) void relayout_k(const float* __restrict__ x,
                                                  const float* __restrict__ w,
                                                  unsigned short* __restrict__ xs,
                                                  unsigned short* __restrict__ wt) {
    if (blockIdx.x >= BATCH * H) {
        int o = (blockIdx.x - BATCH * H) * 256 + threadIdx.x;
        if (o < 9 * COUT * CIN) {
            int cin  = o & (CIN - 1);
            int r    = o >> 7;
            int cout = r & (COUT - 1);
            int tap  = r >> 8;
            wt[o] = f2bf(w[((size_t)cout * CIN + cin) * 9 + tap]);
        }
        return;
    }
    __shared__ __align__(16) unsigned short tile[W * XP];
    const int bh = blockIdx.x;
    const int b  = bh / H;
    const int h  = bh - b * H;
    const float* xr = x + (size_t)b * CIN * (H * W) + (size_t)h * W;
    const int t = threadIdx.x;
    // phase 1: per unit, two float4 loads (c, c+1), pair-writes (ushort2) with
    // per-row 16B-slot rotation (c8+2w)&15 -> writes spread over 8 banks.
#pragma unroll
    for (int i = 0; i < 7; ++i) {
        int e  = t + i * 256;            // < 1792 = 64 cpairs * 28 w4
        int cp = e / 28;
        int w4 = e - cp * 28;
        int c  = cp * 2;
        float4 v0 = *(const float4*)(xr + (size_t)c * (H * W) + w4 * 4);
        float4 v1 = *(const float4*)(xr + (size_t)(c + 1) * (H * W) + w4 * 4);
        int c8 = c >> 3;
        int cl = c & 7;                  // even
        float a0[4] = {v0.x, v0.y, v0.z, v0.w};
        float a1[4] = {v1.x, v1.y, v1.z, v1.w};
#pragma unroll
        for (int j = 0; j < 4; ++j) {
            int ww  = w4 * 4 + j;
            int idx = ww * XP + ((c8 + 2 * ww) & 15) * 8 + cl;
            *(ushort2*)(tile + idx) = (ushort2){f2bf(a0[j]), f2bf(a1[j])};
        }
    }
    __syncthreads();
    // phase 2: b128 LDS reads (rotation-aware, conflict-free), dwordx4 stores
    uint4* dst = (uint4*)(xs + (size_t)bh * (W * CIN));
#pragma unroll
    for (int i = 0; i < 7; ++i) {
        int e  = t + i * 256;            // < 1792 = 112*16
        int ww = e >> 4;
        int c8 = e & 15;
        dst[e] = *(const uint4*)(tile + ww * XP + ((c8 + 2 * ww) & 15) * 8);
    }
}

// ---------- main: BM=256 x BN=192, BK=64, 8 waves, dbuf LDS, counted vmcnt ----------
// LDS per buf: A [256][64] + B [192][64] shorts = 56 KB; dbuf = 112 KB.
// Rows are 128 B -> T2 XOR swizzle: 16B slot s stored at (s ^ (row&7)).
// global_load_lds writes linearly; swizzle realized by pre-swizzled SOURCE.
__global__ __launch_bounds__(512, 2) void conv_mfma_k(const unsigned short* __restrict__ xs,
                                                      const unsigned short* __restrict__ wt,
                                                      float* __restrict__ out) {
    __shared__ __align__(16) unsigned short L[2][(COUT + BN) * 64];  // 114688 B

    const int tid  = threadIdx.x;
    const int wave = tid >> 6;
    const int lane = tid & 63;
    const int wm   = wave >> 2;            // 0..1 -> M offset wm*128
    const int wn   = wave & 3;             // 0..3 -> N offset wn*48
    const int lrow = lane & 15;
    const int kg   = lane >> 4;            // k-group 0..3
    const int n0   = blockIdx.x * BN;

    // staging constants: thread tid stages 16 B at linear LDS byte tid*16 (+call*8192)
    // -> row = call*64 + (tid>>3), slot = tid&7; source k-chunk = slot ^ (row&7).
    const int rA  = tid >> 3;                          // 0..63
    const int sx8 = ((tid & 7) ^ (rA & 7)) * 8;        // source chunk offset (shorts)
    int xbr[3];
#pragma unroll
    for (int c = 0; c < 3; ++c) {
        int nn = n0 + c * 64 + rA;
        if (nn >= NTOT) nn = NTOT - 1;
        int b  = nn / NPIX;
        int rp = nn - b * NPIX;
        int oh = rp / OW;
        int ow = rp - oh * OW;
        xbr[c] = ((b * H + 2 * oh) * W + 2 * ow) * CIN;
    }

    auto stage = [&](int kt, int buf) {
        const int tap  = kt >> 1;
        const int cin0 = (kt & 1) * 64;
        const int r    = (tap >= 6) ? 2 : (tap >= 3) ? 1 : 0;
        const int s    = tap - 3 * r;
        const unsigned short* wsrc = wt + tap * (COUT * CIN) + rA * CIN + cin0 + sx8;
        const unsigned short* xsrc = xs + (r * W + s) * CIN + cin0 + sx8;
        unsigned short* lb = &L[buf][0];
#pragma unroll
        for (int c = 0; c < 4; ++c)            // A: 4 calls x 8 KB
            gld_lds16(wsrc + c * 64 * CIN, lb + c * 4096 + wave * 512);
#pragma unroll
        for (int c = 0; c < 3; ++c)            // B: 3 calls x 8 KB
            gld_lds16(xsrc + xbr[c], lb + 16384 + c * 4096 + wave * 512);
    };

    // swizzled read offsets: logical slot = kh*4 + kg, phys = slot ^ (lrow&7)
    const int aoff = (wm * 128 + lrow) * 64;           // shorts
    const int boff = COUT * 64 + (wn * 48 + lrow) * 64;
    const int sxk0 = ((0 * 4 + kg) ^ (lrow & 7)) * 8;
    const int sxk1 = ((1 * 4 + kg) ^ (lrow & 7)) * 8;

    f32x4 acc[8][3];
#pragma unroll
    for (int mi = 0; mi < 8; ++mi)
#pragma unroll
        for (int ni = 0; ni < 3; ++ni)
            acc[mi][ni] = (f32x4){0.f, 0.f, 0.f, 0.f};

    stage(0, 0);
    stage(1, 1);   // 14 loads in flight

#pragma unroll 2
    for (int kt = 0; kt < 18; ++kt) {
        const int buf = kt & 1;
        // counted wait: drain tile kt's 7 loads, keep tile kt+1's 7 in flight
        if (kt == 17) asm volatile("s_waitcnt vmcnt(0)" ::: "memory");
        else          asm volatile("s_waitcnt vmcnt(7)" ::: "memory");
        asm volatile("s_barrier" ::: "memory");

        const unsigned short* Lb = &L[buf][0];
        bf16x8 a0[8], b0[3], a1[8], b1[3];
        // phase 0 reads (k-half 0)
#pragma unroll
        for (int mi = 0; mi < 8; ++mi)
            a0[mi] = *(const bf16x8*)(Lb + aoff + mi * 1024 + sxk0);
#pragma unroll
        for (int ni = 0; ni < 3; ++ni)
            b0[ni] = *(const bf16x8*)(Lb + boff + ni * 1024 + sxk0);
        asm volatile("s_barrier" ::: "memory");
        // phase 1 reads issued now, land under mfma cluster 0
#pragma unroll
        for (int mi = 0; mi < 8; ++mi)
            a1[mi] = *(const bf16x8*)(Lb + aoff + mi * 1024 + sxk1);
#pragma unroll
        for (int ni = 0; ni < 3; ++ni)
            b1[ni] = *(const bf16x8*)(Lb + boff + ni * 1024 + sxk1);
        __builtin_amdgcn_s_setprio(1);
#pragma unroll
        for (int mi = 0; mi < 8; ++mi)
#pragma unroll
            for (int ni = 0; ni < 3; ++ni)
                acc[mi][ni] = __builtin_amdgcn_mfma_f32_16x16x32_bf16(a0[mi], b0[ni], acc[mi][ni], 0, 0, 0);
        __builtin_amdgcn_s_setprio(0);
        asm volatile("s_barrier" ::: "memory");   // all reads of L[buf] done
        if (kt + 2 < 18) stage(kt + 2, buf);      // overwrite L[buf]; overlaps mfma1
        __builtin_amdgcn_s_setprio(1);
#pragma unroll
        for (int mi = 0; mi < 8; ++mi)
#pragma unroll
            for (int ni = 0; ni < 3; ++ni)
                acc[mi][ni] = __builtin_amdgcn_mfma_f32_16x16x32_bf16(a1[mi], b1[ni], acc[mi][ni], 0, 0, 0);
        __builtin_amdgcn_s_setprio(0);
    }

    // epilogue: D col n = lane&15, row m = (lane>>4)*4 + reg
    long obase[3];
    int  okn[3];
#pragma unroll
    for (int ni = 0; ni < 3; ++ni) {
        int nn = n0 + wn * 48 + ni * 16 + lrow;
        okn[ni] = (nn < NTOT);
        if (!okn[ni]) nn = 0;
        int b   = nn / NPIX;
        int pix = nn - b * NPIX;
        obase[ni] = (long)b * (COUT * NPIX) + pix;
    }
    const int mrow = kg * 4;
#pragma unroll
    for (int mi = 0; mi < 8; ++mi) {
#pragma unroll
        for (int rr = 0; rr < 4; ++rr) {
            int  m  = wm * 128 + mi * 16 + mrow + rr;
            long mo = (long)m * NPIX;
#pragma unroll
            for (int ni = 0; ni < 3; ++ni)
                if (okn[ni]) out[obase[ni] + mo] = acc[mi][ni][rr];
        }
    }
}

// ---------- fallback (ws too small): direct fp32 kernel ----------
__global__ __launch_bounds__(256) void direct_k(const float* __restrict__ x,
                                                const float* __restrict__ w,
                                                float* __restrict__ out) {
    const int pix = blockIdx.x * 256 + threadIdx.x;
    if (pix >= NPIX) return;
    const int b = blockIdx.z, cout0 = blockIdx.y * 8;
    const int oh = pix / OW, ow = pix - oh * OW;
    float acc[8];
#pragma unroll
    for (int i = 0; i < 8; ++i) acc[i] = 0.f;
    const float* xbp = x + ((size_t)b * CIN) * (H * W) + (size_t)(oh * 2) * W + ow * 2;
    const float* wb  = w + (size_t)cout0 * (CIN * 9);
    for (int cin = 0; cin < CIN; ++cin) {
        const float* xp = xbp + (size_t)cin * (H * W);
        float xv[9];
#pragma unroll
        for (int r = 0; r < 3; ++r) {
            xv[r * 3 + 0] = xp[r * W + 0];
            xv[r * 3 + 1] = xp[r * W + 1];
            xv[r * 3 + 2] = xp[r * W + 2];
        }
#pragma unroll
        for (int c = 0; c < 8; ++c) {
            const float* wp = wb + (size_t)c * (CIN * 9) + cin * 9;
#pragma unroll
            for (int k = 0; k < 9; ++k) acc[c] = fmaf(wp[k], xv[k], acc[c]);
        }
    }
    const size_t ob = ((size_t)b * COUT + cout0) * NPIX + pix;
#pragma unroll
    for (int c = 0; c < 8; ++c) out[ob + (size_t)c * NPIX] = acc[c];
}

extern "C" void kernel_launch(void* const* d_in, const int* in_sizes, int n_in,
                              void* d_out, int out_size, void* d_ws, size_t ws_size,
                              hipStream_t stream) {
    const float* x = (const float*)d_in[0];
    const float* w = (const float*)d_in[1];
    float* out = (float*)d_out;

    const size_t xs_elems = (size_t)BATCH * H * W * CIN;
    const size_t wt_elems = (size_t)9 * COUT * CIN;
    const size_t need = (xs_elems + wt_elems) * 2;

    if (ws_size >= need) {
        unsigned short* xs = (unsigned short*)d_ws;
        unsigned short* wt = xs + xs_elems;
        relayout_k<<<dim3(BATCH * H + WBLK), dim3(256), 0, stream>>>(x, w, xs, wt);
        conv_mfma_k<<<dim3(NBLK), dim3(512), 0, stream>>>(xs, wt, out);
    } else {
        dim3 grid((NPIX + 255) / 256, COUT / 8, BATCH);
        direct_k<<<grid, dim3(256), 0, stream>>>(x, w, out);
    }
}

// Round 2
// 381.797 us; speedup vs baseline: 1.0746x; 1.0013x over previous
//
#include <hip/hip_runtime.h>

// Stride-2 valid conv as implicit GEMM on MFMA (bf16 in, fp32 acc).
// GEMM: M=cout=256, N=b*oh*ow=96800, K=tap*cin=1152.
// R5: conv + (T1) bijective XCD swizzle on blockIdx (xs halo reads become L2
//     hits) and (T3-lite) 4x12-MFMA phase interleave: each cluster's ds_reads
//     issued right before it so they land under the previous cluster's MFMAs.
//     Barrier/vmcnt skeleton unchanged from R4 (3 barriers, counted vmcnt(7)).

#define BATCH 32
#define CIN   128
#define H     112
#define W     112
#define COUT  256
#define OH    55
#define OW    55
#define NPIX  (OH*OW)          // 3025
#define NTOT  (BATCH*NPIX)     // 96800

#define BN    192
#define NBLK  ((NTOT + BN - 1) / BN)   // 505

typedef __bf16 bf16x8 __attribute__((ext_vector_type(8)));
typedef float  f32x4  __attribute__((ext_vector_type(4)));

__device__ __forceinline__ unsigned short f2bf(float f) {
    unsigned u = __float_as_uint(f);
    u += 0x7FFFu + ((u >> 16) & 1u);   // RNE
    return (unsigned short)(u >> 16);
}

__device__ __forceinline__ void gld_lds16(const void* g, void* l) {
    __builtin_amdgcn_global_load_lds((__attribute__((address_space(1))) void*)g,
                                     (__attribute__((address_space(3))) void*)l,
                                     16, 0, 0);
}

// ---------- fused prepass ----------
// blocks [0, BATCH*H): x NCHW fp32 -> xs[b][h][w][c] bf16 (LDS transpose)
// blocks [BATCH*H, +1152): w (COUT,CIN,3,3) fp32 -> wt[tap][cout][cin] bf16
#define XP 136   // LDS pitch in shorts (272 B, 16-B aligned)
#define WBLK ((9*COUT*CIN + 255)/256)  // 1152
__global__ __launch_bounds__(256) void relayout_k(const float* __restrict__ x,
                                                  const float* __restrict__ w,
                                                  unsigned short* __restrict__ xs,
                                                  unsigned short* __restrict__ wt) {
    if (blockIdx.x >= BATCH * H) {
        int o = (blockIdx.x - BATCH * H) * 256 + threadIdx.x;
        if (o < 9 * COUT * CIN) {
            int cin  = o & (CIN - 1);
            int r    = o >> 7;
            int cout = r & (COUT - 1);
            int tap  = r >> 8;
            wt[o] = f2bf(w[((size_t)cout * CIN + cin) * 9 + tap]);
        }
        return;
    }
    __shared__ __align__(16) unsigned short tile[W * XP];
    const int bh = blockIdx.x;
    const int b  = bh / H;
    const int h  = bh - b * H;
    const float* xr = x + (size_t)b * CIN * (H * W) + (size_t)h * W;
    const int t = threadIdx.x;
    // phase 1: per unit, two float4 loads (c, c+1), pair-writes (ushort2) with
    // per-row 16B-slot rotation (c8+2w)&15 -> writes spread over 8 banks.
#pragma unroll
    for (int i = 0; i < 7; ++i) {
        int e  = t + i * 256;            // < 1792 = 64 cpairs * 28 w4
        int cp = e / 28;
        int w4 = e - cp * 28;
        int c  = cp * 2;
        float4 v0 = *(const float4*)(xr + (size_t)c * (H * W) + w4 * 4);
        float4 v1 = *(const float4*)(xr + (size_t)(c + 1) * (H * W) + w4 * 4);
        int c8 = c >> 3;
        int cl = c & 7;                  // even
        float a0[4] = {v0.x, v0.y, v0.z, v0.w};
        float a1[4] = {v1.x, v1.y, v1.z, v1.w};
#pragma unroll
        for (int j = 0; j < 4; ++j) {
            int ww  = w4 * 4 + j;
            int idx = ww * XP + ((c8 + 2 * ww) & 15) * 8 + cl;
            *(ushort2*)(tile + idx) = (ushort2){f2bf(a0[j]), f2bf(a1[j])};
        }
    }
    __syncthreads();
    // phase 2: b128 LDS reads (rotation-aware, conflict-free), dwordx4 stores
    uint4* dst = (uint4*)(xs + (size_t)bh * (W * CIN));
#pragma unroll
    for (int i = 0; i < 7; ++i) {
        int e  = t + i * 256;            // < 1792 = 112*16
        int ww = e >> 4;
        int c8 = e & 15;
        dst[e] = *(const uint4*)(tile + ww * XP + ((c8 + 2 * ww) & 15) * 8);
    }
}

// ---------- main: BM=256 x BN=192, BK=64, 8 waves, dbuf LDS, counted vmcnt ----------
// LDS per buf: A [256][64] + B [192][64] shorts = 56 KB; dbuf = 112 KB.
// Rows are 128 B -> T2 XOR swizzle: 16B slot s stored at (s ^ (row&7)).
// global_load_lds writes linearly; swizzle realized by pre-swizzled SOURCE.
__global__ __launch_bounds__(512, 2) void conv_mfma_k(const unsigned short* __restrict__ xs,
                                                      const unsigned short* __restrict__ wt,
                                                      float* __restrict__ out) {
    __shared__ __align__(16) unsigned short L[2][(COUT + BN) * 64];  // 114688 B

    const int tid  = threadIdx.x;
    const int wave = tid >> 6;
    const int lane = tid & 63;
    const int wm   = wave >> 2;            // 0..1 -> M offset wm*128
    const int wn   = wave & 3;             // 0..3 -> N offset wn*48
    const int lrow = lane & 15;
    const int kg   = lane >> 4;            // k-group 0..3

    // T1: bijective XCD swizzle (m204 formula), NBLK = 505 = 8*63 + 1
    const int xcd = blockIdx.x & 7;
    const int lin = blockIdx.x >> 3;
    const int q = NBLK >> 3, r = NBLK & 7;
    const int bswz = (xcd < r ? xcd * (q + 1) : r * (q + 1) + (xcd - r) * q) + lin;
    const int n0 = bswz * BN;

    // staging constants: thread tid stages 16 B at linear LDS byte tid*16 (+call*8192)
    // -> row = call*64 + (tid>>3), slot = tid&7; source k-chunk = slot ^ (row&7).
    const int rA  = tid >> 3;                          // 0..63
    const int sx8 = ((tid & 7) ^ (rA & 7)) * 8;        // source chunk offset (shorts)
    int xbr[3];
#pragma unroll
    for (int c = 0; c < 3; ++c) {
        int nn = n0 + c * 64 + rA;
        if (nn >= NTOT) nn = NTOT - 1;
        int b  = nn / NPIX;
        int rp = nn - b * NPIX;
        int oh = rp / OW;
        int ow = rp - oh * OW;
        xbr[c] = ((b * H + 2 * oh) * W + 2 * ow) * CIN;
    }

    auto stage = [&](int kt, int buf) {
        const int tap  = kt >> 1;
        const int cin0 = (kt & 1) * 64;
        const int r2   = (tap >= 6) ? 2 : (tap >= 3) ? 1 : 0;
        const int s    = tap - 3 * r2;
        const unsigned short* wsrc = wt + tap * (COUT * CIN) + rA * CIN + cin0 + sx8;
        const unsigned short* xsrc = xs + (r2 * W + s) * CIN + cin0 + sx8;
        unsigned short* lb = &L[buf][0];
#pragma unroll
        for (int c = 0; c < 4; ++c)            // A: 4 calls x 8 KB
            gld_lds16(wsrc + c * 64 * CIN, lb + c * 4096 + wave * 512);
#pragma unroll
        for (int c = 0; c < 3; ++c)            // B: 3 calls x 8 KB
            gld_lds16(xsrc + xbr[c], lb + 16384 + c * 4096 + wave * 512);
    };

    // swizzled read offsets: logical slot = kh*4 + kg, phys = slot ^ (lrow&7)
    const int aoff = (wm * 128 + lrow) * 64;           // shorts
    const int boff = COUT * 64 + (wn * 48 + lrow) * 64;
    const int sxk0 = ((0 * 4 + kg) ^ (lrow & 7)) * 8;
    const int sxk1 = ((1 * 4 + kg) ^ (lrow & 7)) * 8;

    f32x4 acc[8][3];
#pragma unroll
    for (int mi = 0; mi < 8; ++mi)
#pragma unroll
        for (int ni = 0; ni < 3; ++ni)
            acc[mi][ni] = (f32x4){0.f, 0.f, 0.f, 0.f};

    stage(0, 0);
    stage(1, 1);   // 14 loads in flight

#pragma unroll 2
    for (int kt = 0; kt < 18; ++kt) {
        const int buf = kt & 1;
        // counted wait: drain tile kt's 7 loads, keep tile kt+1's 7 in flight
        if (kt == 17) asm volatile("s_waitcnt vmcnt(0)" ::: "memory");
        else          asm volatile("s_waitcnt vmcnt(7)" ::: "memory");
        asm volatile("s_barrier" ::: "memory");

        const unsigned short* Lb = &L[buf][0];
        bf16x8 aL[4], aH[4], b0[3], b1[3];
        // ---- P1 reads: A rows 0-63 (k-half 0) + B (k-half 0) ----
#pragma unroll
        for (int mi = 0; mi < 4; ++mi)
            aL[mi] = *(const bf16x8*)(Lb + aoff + mi * 1024 + sxk0);
#pragma unroll
        for (int ni = 0; ni < 3; ++ni)
            b0[ni] = *(const bf16x8*)(Lb + boff + ni * 1024 + sxk0);
        asm volatile("s_barrier" ::: "memory");   // pacing: align wave phases
        __builtin_amdgcn_s_setprio(1);
#pragma unroll
        for (int mi = 0; mi < 4; ++mi)
#pragma unroll
            for (int ni = 0; ni < 3; ++ni)
                acc[mi][ni] = __builtin_amdgcn_mfma_f32_16x16x32_bf16(aL[mi], b0[ni], acc[mi][ni], 0, 0, 0);
        __builtin_amdgcn_s_setprio(0);
        // ---- P2 reads: A rows 64-127 (k-half 0); land under cluster 1 ----
#pragma unroll
        for (int mi = 0; mi < 4; ++mi)
            aH[mi] = *(const bf16x8*)(Lb + aoff + (mi + 4) * 1024 + sxk0);
        __builtin_amdgcn_s_setprio(1);
#pragma unroll
        for (int mi = 0; mi < 4; ++mi)
#pragma unroll
            for (int ni = 0; ni < 3; ++ni)
                acc[mi + 4][ni] = __builtin_amdgcn_mfma_f32_16x16x32_bf16(aH[mi], b0[ni], acc[mi + 4][ni], 0, 0, 0);
        __builtin_amdgcn_s_setprio(0);
        // ---- P3 reads: A rows 0-63 (k-half 1) + B (k-half 1) ----
#pragma unroll
        for (int mi = 0; mi < 4; ++mi)
            aL[mi] = *(const bf16x8*)(Lb + aoff + mi * 1024 + sxk1);
#pragma unroll
        for (int ni = 0; ni < 3; ++ni)
            b1[ni] = *(const bf16x8*)(Lb + boff + ni * 1024 + sxk1);
        __builtin_amdgcn_s_setprio(1);
#pragma unroll
        for (int mi = 0; mi < 4; ++mi)
#pragma unroll
            for (int ni = 0; ni < 3; ++ni)
                acc[mi][ni] = __builtin_amdgcn_mfma_f32_16x16x32_bf16(aL[mi], b1[ni], acc[mi][ni], 0, 0, 0);
        __builtin_amdgcn_s_setprio(0);
        // ---- P4 reads: A rows 64-127 (k-half 1) ----
#pragma unroll
        for (int mi = 0; mi < 4; ++mi)
            aH[mi] = *(const bf16x8*)(Lb + aoff + (mi + 4) * 1024 + sxk1);
        asm volatile("s_barrier" ::: "memory");   // all reads of L[buf] issued
        if (kt + 2 < 18) stage(kt + 2, buf);      // overwrite L[buf]; overlaps cluster 4
        __builtin_amdgcn_s_setprio(1);
#pragma unroll
        for (int mi = 0; mi < 4; ++mi)
#pragma unroll
            for (int ni = 0; ni < 3; ++ni)
                acc[mi + 4][ni] = __builtin_amdgcn_mfma_f32_16x16x32_bf16(aH[mi], b1[ni], acc[mi + 4][ni], 0, 0, 0);
        __builtin_amdgcn_s_setprio(0);
    }

    // epilogue: D col n = lane&15, row m = (lane>>4)*4 + reg
    long obase[3];
    int  okn[3];
#pragma unroll
    for (int ni = 0; ni < 3; ++ni) {
        int nn = n0 + wn * 48 + ni * 16 + lrow;
        okn[ni] = (nn < NTOT);
        if (!okn[ni]) nn = 0;
        int b   = nn / NPIX;
        int pix = nn - b * NPIX;
        obase[ni] = (long)b * (COUT * NPIX) + pix;
    }
    const int mrow = kg * 4;
#pragma unroll
    for (int mi = 0; mi < 8; ++mi) {
#pragma unroll
        for (int rr = 0; rr < 4; ++rr) {
            int  m  = mi * 16 + mrow + rr + wm * 128;
            long mo = (long)m * NPIX;
#pragma unroll
            for (int ni = 0; ni < 3; ++ni)
                if (okn[ni]) out[obase[ni] + mo] = acc[mi][ni][rr];
        }
    }
}

// ---------- fallback (ws too small): direct fp32 kernel ----------
__global__ __launch_bounds__(256) void direct_k(const float* __restrict__ x,
                                                const float* __restrict__ w,
                                                float* __restrict__ out) {
    const int pix = blockIdx.x * 256 + threadIdx.x;
    if (pix >= NPIX) return;
    const int b = blockIdx.z, cout0 = blockIdx.y * 8;
    const int oh = pix / OW, ow = pix - oh * OW;
    float acc[8];
#pragma unroll
    for (int i = 0; i < 8; ++i) acc[i] = 0.f;
    const float* xbp = x + ((size_t)b * CIN) * (H * W) + (size_t)(oh * 2) * W + ow * 2;
    const float* wb  = w + (size_t)cout0 * (CIN * 9);
    for (int cin = 0; cin < CIN; ++cin) {
        const float* xp = xbp + (size_t)cin * (H * W);
        float xv[9];
#pragma unroll
        for (int r = 0; r < 3; ++r) {
            xv[r * 3 + 0] = xp[r * W + 0];
            xv[r * 3 + 1] = xp[r * W + 1];
            xv[r * 3 + 2] = xp[r * W + 2];
        }
#pragma unroll
        for (int c = 0; c < 8; ++c) {
            const float* wp = wb + (size_t)c * (CIN * 9) + cin * 9;
#pragma unroll
            for (int k = 0; k < 9; ++k) acc[c] = fmaf(wp[k], xv[k], acc[c]);
        }
    }
    const size_t ob = ((size_t)b * COUT + cout0) * NPIX + pix;
#pragma unroll
    for (int c = 0; c < 8; ++c) out[ob + (size_t)c * NPIX] = acc[c];
}

extern "C" void kernel_launch(void* const* d_in, const int* in_sizes, int n_in,
                              void* d_out, int out_size, void* d_ws, size_t ws_size,
                              hipStream_t stream) {
    const float* x = (const float*)d_in[0];
    const float* w = (const float*)d_in[1];
    float* out = (float*)d_out;

    const size_t xs_elems = (size_t)BATCH * H * W * CIN;
    const size_t wt_elems = (size_t)9 * COUT * CIN;
    const size_t need = (xs_elems + wt_elems) * 2;

    if (ws_size >= need) {
        unsigned short* xs = (unsigned short*)d_ws;
        unsigned short* wt = xs + xs_elems;
        relayout_k<<<dim3(BATCH * H + WBLK), dim3(256), 0, stream>>>(x, w, xs, wt);
        conv_mfma_k<<<dim3(NBLK), dim3(512), 0, stream>>>(xs, wt, out);
    } else {
        dim3 grid((NPIX + 255) / 256, COUT / 8, BATCH);
        direct_k<<<grid, dim3(256), 0, stream>>>(x, w, out);
    }
}